// Round 7
// baseline (171.104 us; speedup 1.0000x reference)
//
#include <hip/hip_runtime.h>
#include <cstdint>

#define DIM 128
#define NCEN 8

typedef __attribute__((ext_vector_type(8))) short short8;   // 8 bf16
typedef _Float16 half8 __attribute__((ext_vector_type(8))); // 8 fp16
typedef __attribute__((ext_vector_type(4))) float f32x4;

constexpr float TAU   = 1e-5f;    // margin threshold for exact-recompute
constexpr float SCL   = 4096.0f;  // 2^12 pre-scale (dodge fp16 subnormals)
constexpr float UNSCL = 1.0f / (SCL * SCL);  // 2^-24, exact

__device__ __forceinline__ unsigned bf16rne(float f) {
    unsigned u = __float_as_uint(f);
    return (u + 0x7FFFu + ((u >> 16) & 1u)) >> 16;
}

// ============ Kernel A: xr = (x/||x||) @ Pi^T  via split-fp16 MFMA ============
constexpr int A_BLOCK = 512;
constexpr int A_TPW   = 2;               // 16-row tiles per wave
constexpr int A_RPB   = 8 * 16 * A_TPW;  // 256 rows per block

__global__ __launch_bounds__(A_BLOCK, 4)
void k_rotate(const float* __restrict__ x, const float* __restrict__ Pi,
              float* __restrict__ xr_out)
{
    // Pi*4096 as fp16 hi/lo, row-major [d][k], 16B chunks XOR-swizzled by d&7
    __shared__ _Float16 bh[DIM * DIM];   // 32 KB
    __shared__ _Float16 bl[DIM * DIM];   // 32 KB

    const int tid  = threadIdx.x;
    const int wave = tid >> 6;
    const int lane = tid & 63;
    const int m = lane & 15, q = lane >> 4;

    // ---- stage split Pi ----
    {
        const int d  = tid >> 2;
        const int qt = tid & 3;
        const float* pr = Pi + (size_t)d * DIM + qt * 32;
        const int swz = d & 7;
#pragma unroll
        for (int c = 0; c < 4; ++c) {
            float4 v0 = *reinterpret_cast<const float4*>(pr + c * 8);
            float4 v1 = *reinterpret_cast<const float4*>(pr + c * 8 + 4);
            float vv[8] = {v0.x, v0.y, v0.z, v0.w, v1.x, v1.y, v1.z, v1.w};
            half8 hv, lv;
#pragma unroll
            for (int j = 0; j < 8; ++j) {
                float s = vv[j] * SCL;
                _Float16 h = (_Float16)s;
                hv[j] = h;
                lv[j] = (_Float16)(s - (float)h);
            }
            const int off = d * DIM + ((qt * 4 + c) ^ swz) * 8;
            *reinterpret_cast<half8*>(bh + off) = hv;
            *reinterpret_cast<half8*>(bl + off) = lv;
        }
    }
    __syncthreads();

    for (int t = 0; t < A_TPW; ++t) {
        const int rowbase = blockIdx.x * A_RPB + (wave * A_TPW + t) * 16;

        // x in MFMA-A layout: row m, k = kf*32 + q*8 + j
        const float* xp = x + (size_t)(rowbase + m) * DIM + q * 8;
        float xv[4][8];
#pragma unroll
        for (int kf = 0; kf < 4; ++kf) {
            *reinterpret_cast<float4*>(&xv[kf][0]) = *reinterpret_cast<const float4*>(xp + kf * 32);
            *reinterpret_cast<float4*>(&xv[kf][4]) = *reinterpret_cast<const float4*>(xp + kf * 32 + 4);
        }

        // fast norm (order-free; flagged path redoes numpy-order exactly)
        float s = 0.f;
#pragma unroll
        for (int kf = 0; kf < 4; ++kf)
#pragma unroll
            for (int j = 0; j < 8; ++j) s = fmaf(xv[kf][j], xv[kf][j], s);
        s += __shfl_xor(s, 16, 64);
        s += __shfl_xor(s, 32, 64);
        const float vne   = __fadd_rn(__fsqrt_rn(s), 1e-8f);
        const float inv4k = __fdiv_rn(1.0f, vne) * SCL;   // *2^12 exact

        // fp16 split of scaled normalized x
        half8 xh[4], xl[4];
#pragma unroll
        for (int kf = 0; kf < 4; ++kf)
#pragma unroll
            for (int j = 0; j < 8; ++j) {
                float xs = xv[kf][j] * inv4k;
                _Float16 h = (_Float16)xs;
                xh[kf][j] = h;
                xl[kf][j] = (_Float16)(xs - (float)h);
            }

        // mm1: 4 MFMAs per (nt,kf) — all split cross terms kept
#pragma unroll
        for (int nt = 0; nt < 8; ++nt) {
            const int d   = nt * 16 + m;
            const int ro  = d * DIM;
            const int swz = d & 7;
            f32x4 acc = {0.f, 0.f, 0.f, 0.f};
#pragma unroll
            for (int kf = 0; kf < 4; ++kf) {
                const int off = ro + ((kf * 4 + q) ^ swz) * 8;
                half8 ph = *reinterpret_cast<const half8*>(bh + off);
                half8 pl = *reinterpret_cast<const half8*>(bl + off);
                acc = __builtin_amdgcn_mfma_f32_16x16x32_f16(xl[kf], pl, acc, 0, 0, 0);
                acc = __builtin_amdgcn_mfma_f32_16x16x32_f16(xh[kf], pl, acc, 0, 0, 0);
                acc = __builtin_amdgcn_mfma_f32_16x16x32_f16(xl[kf], ph, acc, 0, 0, 0);
                acc = __builtin_amdgcn_mfma_f32_16x16x32_f16(xh[kf], ph, acc, 0, 0, 0);
            }
            // C/D: col = lane&15, row = (lane>>4)*4 + reg  [HW-verified round 5]
#pragma unroll
            for (int qq = 0; qq < 4; ++qq)
                xr_out[(size_t)(rowbase + q * 4 + qq) * DIM + nt * 16 + m] = acc[qq] * UNSCL;
        }
    }
}

// ===== Kernel BC: quantize (flag-protected) + z + mm2 (bf16 MFMA) + *vn =====
constexpr int B_BLOCK = 256;
constexpr int B_TPW   = 2;
constexpr int B_RPB   = 4 * 16 * B_TPW;  // 128 rows per block

__global__ __launch_bounds__(B_BLOCK, 4)
void k_quant_unrot(const float* __restrict__ x, const float* __restrict__ Pi,
                   const float* __restrict__ cen, float* __restrict__ io)
{
    __shared__ unsigned short piT[DIM * DIM];   // bf16 Pi^T for mm2, 32 KB

    const int tid  = threadIdx.x;
    const int wave = tid >> 6;
    const int lane = tid & 63;
    const int m = lane & 15, q = lane >> 4;

    // ---- stage transposed bf16 Pi (round-5-proven) ----
#pragma unroll
    for (int sblk = 0; sblk < 4; ++sblk) {
        int sub = tid + sblk * B_BLOCK;   // 0..1023
        int a4 = (sub & 31) * 4;          // k base
        int b4 = (sub >> 5) * 4;          // n base
        float rv[4][4];
#pragma unroll
        for (int i = 0; i < 4; ++i)
            *reinterpret_cast<float4*>(rv[i]) =
                *reinterpret_cast<const float4*>(Pi + (size_t)(a4 + i) * DIM + b4);
#pragma unroll
        for (int j = 0; j < 4; ++j) {
            const int n   = b4 + j;
            const int ksw = a4 ^ ((n & 7) << 3);
            unsigned lo = bf16rne(rv[0][j]) | (bf16rne(rv[1][j]) << 16);
            unsigned hi = bf16rne(rv[2][j]) | (bf16rne(rv[3][j]) << 16);
            *reinterpret_cast<uint2*>(&piT[n * DIM + ksw]) = make_uint2(lo, hi);
        }
    }
    __syncthreads();

    float cv[NCEN], mm[NCEN - 1];
#pragma unroll
    for (int i = 0; i < NCEN; ++i) cv[i] = cen[i];
#pragma unroll
    for (int i = 0; i < NCEN - 1; ++i) mm[i] = 0.5f * (cv[i] + cv[i + 1]);

    for (int t = 0; t < B_TPW; ++t) {
        const int rowbase = blockIdx.x * B_RPB + (wave * B_TPW + t) * 16;

        // xr in A-layout (all loads precede all in-place stores)
        const float* vp = io + (size_t)(rowbase + m) * DIM + q * 8;
        float v[4][8];
#pragma unroll
        for (int kf = 0; kf < 4; ++kf) {
            *reinterpret_cast<float4*>(&v[kf][0]) = *reinterpret_cast<const float4*>(vp + kf * 32);
            *reinterpret_cast<float4*>(&v[kf][4]) = *reinterpret_cast<const float4*>(vp + kf * 32 + 4);
        }

        // fast vn from raw x (smooth use only: final scale)
        const float* xp = x + (size_t)(rowbase + m) * DIM + q * 8;
        float s = 0.f;
#pragma unroll
        for (int kf = 0; kf < 4; ++kf) {
            float4 a = *reinterpret_cast<const float4*>(xp + kf * 32);
            float4 b = *reinterpret_cast<const float4*>(xp + kf * 32 + 4);
            s = fmaf(a.x, a.x, s); s = fmaf(a.y, a.y, s);
            s = fmaf(a.z, a.z, s); s = fmaf(a.w, a.w, s);
            s = fmaf(b.x, b.x, s); s = fmaf(b.y, b.y, s);
            s = fmaf(b.z, b.z, s); s = fmaf(b.w, b.w, s);
        }
        s += __shfl_xor(s, 16, 64);
        s += __shfl_xor(s, 32, 64);
        const float vn = __fsqrt_rn(s);

        // ---- quantize with margin flag ----
        float qv[4][8], rs[4][8];
        unsigned sgb = 0u, flg = 0u;
        float as = 0.f;
#pragma unroll
        for (int kf = 0; kf < 4; ++kf)
#pragma unroll
            for (int j = 0; j < 8; ++j) {
                const float xr = v[kf][j];
                float t0   = __fsub_rn(xr, mm[0]);
                float qq   = (t0 > 0.f) ? cv[1] : cv[0];
                float dmin = fabsf(t0);
#pragma unroll
                for (int i = 1; i < NCEN - 1; ++i) {
                    float ti = __fsub_rn(xr, mm[i]);
                    qq   = (ti > 0.f) ? cv[i + 1] : qq;
                    dmin = fminf(dmin, fabsf(ti));
                }
                float res = __fsub_rn(xr, qq);
                float ar  = fabsf(res);
                dmin = fminf(dmin, ar);
                qv[kf][j] = qq;
                rs[kf][j] = res;
                const int bit = kf * 8 + j;
                if (res >= 0.f)  sgb |= 1u << bit;
                if (dmin < TAU)  flg |= 1u << bit;
                as += ar;
            }

        // ---- rare exact-recompute path (reproduces reference f32 pipeline) ----
        if (flg) {
            const float* xrow = x + (size_t)(rowbase + m) * DIM;
            unsigned ff = flg;
            while (ff) {
                const int b = __builtin_ctz(ff);
                ff &= ff - 1;
                const int d = (b >> 3) * 32 + q * 8 + (b & 7);
                const float* prow = Pi + (size_t)d * DIM;
                // numpy-order norm: r[j] = sum_t x[j+8t]^2 sequential, pairwise tree
                float r8[8] = {0.f, 0.f, 0.f, 0.f, 0.f, 0.f, 0.f, 0.f};
                for (int c8 = 0; c8 < 8; ++c8) {
                    float xc[16];
#pragma unroll
                    for (int i = 0; i < 4; ++i)
                        *reinterpret_cast<float4*>(&xc[4 * i]) =
                            *reinterpret_cast<const float4*>(xrow + c8 * 16 + 4 * i);
#pragma unroll
                    for (int tl = 0; tl < 2; ++tl)
#pragma unroll
                        for (int jj = 0; jj < 8; ++jj)
                            r8[jj] = fmaf(xc[tl * 8 + jj], xc[tl * 8 + jj], r8[jj]);
                }
                float rr = __fadd_rn(
                    __fadd_rn(__fadd_rn(r8[0], r8[1]), __fadd_rn(r8[2], r8[3])),
                    __fadd_rn(__fadd_rn(r8[4], r8[5]), __fadd_rn(r8[6], r8[7])));
                const float vneX = __fadd_rn(__fsqrt_rn(rr), 1e-8f);
                // exact ascending-k chain
                float accX = 0.f;
                for (int c8 = 0; c8 < 8; ++c8) {
                    float xc[16], pc[16];
#pragma unroll
                    for (int i = 0; i < 4; ++i) {
                        *reinterpret_cast<float4*>(&xc[4 * i]) =
                            *reinterpret_cast<const float4*>(xrow + c8 * 16 + 4 * i);
                        *reinterpret_cast<float4*>(&pc[4 * i]) =
                            *reinterpret_cast<const float4*>(prow + c8 * 16 + 4 * i);
                    }
#pragma unroll
                    for (int kk = 0; kk < 16; ++kk)
                        accX = fmaf(__fdiv_rn(xc[kk], vneX), pc[kk], accX);
                }
                // exact f32 d2-argmin, first-min tie-break
                float dd   = __fsub_rn(accX, cv[0]);
                float best = __fmul_rn(dd, dd);
                float qe   = cv[0];
#pragma unroll
                for (int i = 1; i < NCEN; ++i) {
                    float di = __fsub_rn(accX, cv[i]);
                    float d2 = __fmul_rn(di, di);
                    bool  c  = d2 < best;
                    best = c ? d2 : best;
                    qe   = c ? cv[i] : qe;
                }
                const float rese = __fsub_rn(accX, qe);
                // static-index gather/scatter (avoid scratch)
                float rold = 0.f;
#pragma unroll
                for (int s32 = 0; s32 < 32; ++s32)
                    if (s32 == b) rold = rs[s32 >> 3][s32 & 7];
                as = as - fabsf(rold) + fabsf(rese);
#pragma unroll
                for (int s32 = 0; s32 < 32; ++s32)
                    if (s32 == b) qv[s32 >> 3][s32 & 7] = qe;
                sgb = (rese >= 0.f) ? (sgb | (1u << b)) : (sgb & ~(1u << b));
            }
        }

        // ---- residual scale + z (bf16, already in mm2 A-layout) ----
        as += __shfl_xor(as, 16, 64);
        as += __shfl_xor(as, 32, 64);
        const float sc = as * (1.0f / 128.0f);
        short8 zfr[4];
#pragma unroll
        for (int kf = 0; kf < 4; ++kf)
#pragma unroll
            for (int j = 0; j < 8; ++j) {
                float z = __fadd_rn(qv[kf][j], ((sgb >> (kf * 8 + j)) & 1u) ? sc : -sc);
                zfr[kf][j] = (short)bf16rne(z);
            }

        // ---- mm2 + *vn, in-place out ----
        float vnr[4];
#pragma unroll
        for (int qq = 0; qq < 4; ++qq) vnr[qq] = __shfl(vn, q * 4 + qq, 64);

#pragma unroll
        for (int nt = 0; nt < 8; ++nt) {
            const int n = nt * 16 + m;
            f32x4 acc = {0.f, 0.f, 0.f, 0.f};
#pragma unroll
            for (int kf = 0; kf < 4; ++kf) {
                const int k0  = kf * 32 + q * 8;
                const int ksw = k0 ^ ((n & 7) << 3);
                short8 bfr = *reinterpret_cast<const short8*>(&piT[n * DIM + ksw]);
                acc = __builtin_amdgcn_mfma_f32_16x16x32_bf16(zfr[kf], bfr, acc, 0, 0, 0);
            }
#pragma unroll
            for (int qq = 0; qq < 4; ++qq)
                io[(size_t)(rowbase + q * 4 + qq) * DIM + n] = __fmul_rn(acc[qq], vnr[qq]);
        }
    }
}

extern "C" void kernel_launch(void* const* d_in, const int* in_sizes, int n_in,
                              void* d_out, int out_size, void* d_ws, size_t ws_size,
                              hipStream_t stream) {
    const float* x   = (const float*)d_in[0];
    const float* Pi  = (const float*)d_in[1];
    const float* cen = (const float*)d_in[2];
    float* outp      = (float*)d_out;

    const int n_rows = in_sizes[0] / DIM;

    hipLaunchKernelGGL(k_rotate, dim3(n_rows / A_RPB), dim3(A_BLOCK), 0, stream,
                       x, Pi, outp);
    hipLaunchKernelGGL(k_quant_unrot, dim3(n_rows / B_RPB), dim3(B_BLOCK), 0, stream,
                       x, Pi, cen, outp);
}